// Round 2
// baseline (3396.192 us; speedup 1.0000x reference)
//
#include <hip/hip_runtime.h>

#define T_LEN 4096
#define B_SZ  256

typedef float v2f __attribute__((ext_vector_type(2)));

__device__ __forceinline__ float fexp2(float x) { return __builtin_amdgcn_exp2f(x); }
__device__ __forceinline__ float frcp(float x)  { return __builtin_amdgcn_rcpf(x); }

// Pin a value into a VGPR so the compiler cannot rematerialize the load
// inside the recurrent loop (round-1 evidence: VGPR_Count=56 < 73 live
// weight floats => weights were being re-loaded every timestep).
#define PIN2(v) asm volatile("" : "+v"(v))
#define PINF(v) asm volatile("" : "+v"(v))

// ---------------------------------------------------------------------------
// Init: y1 <- bl1 broadcast, out <- bl2 broadcast (biases of the two linears).
// ---------------------------------------------------------------------------
__global__ void init_bias_kernel(const float* __restrict__ bl1,
                                 const float* __restrict__ bl2,
                                 float* __restrict__ y1,
                                 float* __restrict__ out)
{
    const long idx = (long)blockIdx.x * blockDim.x + threadIdx.x; // over B*T
    float4 a1 = make_float4(bl1[0], bl1[1], bl1[2], bl1[3]);
    float4 b1 = make_float4(bl1[4], bl1[5], bl1[6], bl1[7]);
    float4 a2 = make_float4(bl2[0], bl2[1], bl2[2], bl2[3]);
    float4 b2 = make_float4(bl2[4], bl2[5], bl2[6], bl2[7]);
    float4* y4 = (float4*)y1;
    float4* o4 = (float4*)out;
    y4[idx * 2 + 0] = a1;
    y4[idx * 2 + 1] = b1;
    o4[idx * 2 + 0] = a2;
    o4[idx * 2 + 1] = b2;
}

// ---------------------------------------------------------------------------
// One bidirectional LSTM layer + fused (lagged, atomic) output projection.
// Cell (batch, dir) on 8 lanes; lane j owns hidden unit j and gate rows
// {j, 8+j, 16+j, 24+j} (i,f,g,o). 8 cells/wave, 1 wave/block, 64 blocks.
// Gate pairs packed as <2 x float> to get v_pk_fma_f32.
// Weights pre-scaled by -log2(e) (sigmoid) / -2log2(e) (tanh) so each
// activation is rcp(1+exp2(z)).
// ---------------------------------------------------------------------------
__global__ __launch_bounds__(64, 1)
void lstm_layer_kernel(const float* __restrict__ x,     // [B,T,8]
                       const float* __restrict__ WihF, const float* __restrict__ WhhF,
                       const float* __restrict__ biasF,
                       const float* __restrict__ WihB, const float* __restrict__ WhhB,
                       const float* __restrict__ biasB,
                       const float* __restrict__ Wproj, // [8][16]
                       float* __restrict__ y)           // [B,T,8], pre-inited w/ bias
{
    const int tid  = threadIdx.x;
    const int j    = tid & 7;
    const int cell = blockIdx.x * 8 + (tid >> 3);
    const int isB  = cell >> 8;          // uniform per block
    const int b    = cell & 255;

    const float* Wih  = isB ? WihB : WihF;
    const float* Whh  = isB ? WhhB : WhhF;
    const float* bias = isB ? biasB : biasF;

    const float NL2E = -1.4426950408889634f;
    const float GSC  = 2.0f * NL2E;

    // Pair A = gates (i,f) rows {j, 8+j}; pair B = gates (g,o) rows {16+j, 24+j}
    v2f WiA[8], WiB[8], WhA[8], WhB[8];
    #pragma unroll
    for (int k = 0; k < 8; ++k) {
        WiA[k] = (v2f){Wih[(0 * 8 + j) * 8 + k] * NL2E, Wih[(1 * 8 + j) * 8 + k] * NL2E};
        WiB[k] = (v2f){Wih[(2 * 8 + j) * 8 + k] * GSC,  Wih[(3 * 8 + j) * 8 + k] * NL2E};
        WhA[k] = (v2f){Whh[(0 * 8 + j) * 8 + k] * NL2E, Whh[(1 * 8 + j) * 8 + k] * NL2E};
        WhB[k] = (v2f){Whh[(2 * 8 + j) * 8 + k] * GSC,  Whh[(3 * 8 + j) * 8 + k] * NL2E};
    }
    v2f bA = (v2f){bias[j] * NL2E,      bias[8 + j] * NL2E};
    v2f bB = (v2f){bias[16 + j] * GSC,  bias[24 + j] * NL2E};
    float Wc[8];
    #pragma unroll
    for (int k = 0; k < 8; ++k) Wc[k] = Wproj[j * 16 + isB * 8 + k];

    // Pin everything loop-invariant into registers.
    #pragma unroll
    for (int k = 0; k < 8; ++k) {
        PIN2(WiA[k]); PIN2(WiB[k]); PIN2(WhA[k]); PIN2(WhB[k]); PINF(Wc[k]);
    }
    PIN2(bA); PIN2(bB);

    const int  st    = isB ? -1 : 1;
    const long start = isB ? (T_LEN - 1) : 0;
    const int  xstep = st * 2;                 // in float4 units
    const long wstep = (long)st * 8;           // in float units

    const float4* xc = (const float4*)x + ((long)b * T_LEN + start) * 2;
    float*        wp = y + ((long)b * T_LEN + start) * 8 + j;

    float c = 0.0f, h = 0.0f;
    float4 xa = xc[0], xb = xc[1];

    for (int t = 0; t < T_LEN; ++t) {
        // ---- prefetch x_{t+1} (clamped at the end) — issued before anything
        // else so the dependent wait next iteration excludes the atomic.
        const float4* xn = (t == T_LEN - 1) ? xc : (xc + xstep);
        float4 nxa = xn[0];
        float4 nxb = xn[1];

        // ---- broadcast previous h across the cell's 8 lanes (issue DS early)
        float hb[8];
        #pragma unroll
        for (int k = 0; k < 8; ++k) hb[k] = __shfl(h, k, 8);

        // ---- input projection (independent of h; overlaps DS latency)
        float xv[8] = {xa.x, xa.y, xa.z, xa.w, xb.x, xb.y, xb.z, xb.w};
        v2f accA = bA, accB = bB;
        #pragma unroll
        for (int k = 0; k < 8; ++k) {
            v2f xs = (v2f){xv[k], xv[k]};
            accA = __builtin_elementwise_fma(WiA[k], xs, accA);
            accB = __builtin_elementwise_fma(WiB[k], xs, accB);
        }

        // ---- fused output projection for step t-1 (hb holds h_{t-1})
        if (t > 0) {
            float contrib = 0.0f;
            #pragma unroll
            for (int k = 0; k < 8; ++k) contrib = fmaf(hb[k], Wc[k], contrib);
            atomicAdd(wp, contrib);
            wp += wstep;
        }

        // ---- hidden projection
        #pragma unroll
        for (int k = 0; k < 8; ++k) {
            v2f hs = (v2f){hb[k], hb[k]};
            accA = __builtin_elementwise_fma(WhA[k], hs, accA);
            accB = __builtin_elementwise_fma(WhB[k], hs, accB);
        }

        // ---- activations: sigma(z) = rcp(1+exp2(zs)), tanh = 2*sigma(2z)-1
        const float si = frcp(1.0f + fexp2(accA.x));
        const float sf = frcp(1.0f + fexp2(accA.y));
        const float tg = 2.0f * frcp(1.0f + fexp2(accB.x)) - 1.0f;
        const float so = frcp(1.0f + fexp2(accB.y));

        c = fmaf(sf, c, si * tg);
        const float th = 2.0f * frcp(1.0f + fexp2(GSC * c)) - 1.0f;
        h = so * th;

        xa = nxa; xb = nxb; xc = xn;
    }

    // tail: contribution of the final h
    {
        float hb[8];
        #pragma unroll
        for (int k = 0; k < 8; ++k) hb[k] = __shfl(h, k, 8);
        float contrib = 0.0f;
        #pragma unroll
        for (int k = 0; k < 8; ++k) contrib = fmaf(hb[k], Wc[k], contrib);
        atomicAdd(wp, contrib);
    }
}

extern "C" void kernel_launch(void* const* d_in, const int* in_sizes, int n_in,
                              void* d_out, int out_size, void* d_ws, size_t ws_size,
                              hipStream_t stream)
{
    const float* x     = (const float*)d_in[0];
    const float* Wih1f = (const float*)d_in[1];
    const float* Whh1f = (const float*)d_in[2];
    const float* b1f   = (const float*)d_in[3];
    const float* Wih1b = (const float*)d_in[4];
    const float* Whh1b = (const float*)d_in[5];
    const float* b1b   = (const float*)d_in[6];
    const float* Wih2f = (const float*)d_in[7];
    const float* Whh2f = (const float*)d_in[8];
    const float* b2f   = (const float*)d_in[9];
    const float* Wih2b = (const float*)d_in[10];
    const float* Whh2b = (const float*)d_in[11];
    const float* b2b   = (const float*)d_in[12];
    const float* W1    = (const float*)d_in[13];
    const float* bl1   = (const float*)d_in[14];
    const float* W2    = (const float*)d_in[15];
    const float* bl2   = (const float*)d_in[16];

    float* out = (float*)d_out;
    float* y1  = (float*)d_ws;   // [B,T,8] fp32 = 32 MB

    const int BT = B_SZ * T_LEN;

    init_bias_kernel<<<BT / 256, 256, 0, stream>>>(bl1, bl2, y1, out);

    lstm_layer_kernel<<<64, 64, 0, stream>>>(x, Wih1f, Whh1f, b1f,
                                             Wih1b, Whh1b, b1b, W1, y1);

    lstm_layer_kernel<<<64, 64, 0, stream>>>(y1, Wih2f, Whh2f, b2f,
                                             Wih2b, Whh2b, b2b, W2, out);
}

// Round 4
// 1500.136 us; speedup vs baseline: 2.2639x; 2.2639x over previous
//
#include <hip/hip_runtime.h>

#define T_LEN 4096
#define B_SZ  256

__device__ __forceinline__ float fexp2(float x) { return __builtin_amdgcn_exp2f(x); }
__device__ __forceinline__ float frcp(float x)  { return __builtin_amdgcn_rcpf(x); }
__device__ __forceinline__ float bperm(int byteaddr, float v) {
    return __int_as_float(__builtin_amdgcn_ds_bpermute(byteaddr, __float_as_int(v)));
}
// quad_perm broadcast: CTRL = k*0x55 broadcasts quad-lane k to all 4 lanes.
template<int CTRL>
__device__ __forceinline__ float dppq(float v) {
    return __int_as_float(__builtin_amdgcn_update_dpp(
        0, __float_as_int(v), CTRL, 0xf, 0xf, true));
}

// ---------------------------------------------------------------------------
// Init: y1 <- bl1 broadcast, out <- bl2 broadcast. Recurrent kernels
// atomic-add their projected h contributions on top.
// ---------------------------------------------------------------------------
__global__ void init_bias_kernel(const float* __restrict__ bl1,
                                 const float* __restrict__ bl2,
                                 float* __restrict__ y1,
                                 float* __restrict__ out)
{
    const long idx = (long)blockIdx.x * blockDim.x + threadIdx.x; // over B*T
    float4 a1 = make_float4(bl1[0], bl1[1], bl1[2], bl1[3]);
    float4 b1 = make_float4(bl1[4], bl1[5], bl1[6], bl1[7]);
    float4 a2 = make_float4(bl2[0], bl2[1], bl2[2], bl2[3]);
    float4 b2 = make_float4(bl2[4], bl2[5], bl2[6], bl2[7]);
    float4* y4 = (float4*)y1;
    float4* o4 = (float4*)out;
    y4[idx * 2 + 0] = a1;
    y4[idx * 2 + 1] = b1;
    o4[idx * 2 + 0] = a2;
    o4[idx * 2 + 1] = b2;
}

// ---------------------------------------------------------------------------
// Recurrence, one direction (ST = +1 fwd / -1 bwd), 2 cells per wave.
// Lane r (0..31 within cell): unit j = r>>2, gate g = r&3 (i,f,g,o).
// Per step: 8x ds_bpermute (h broadcast, the only DS on the chain),
// 8 fma input proj (off-chain, x from register ring), 8 fma hidden matvec,
// one exp2+rcp activation per lane, 4x quad_perm DPP gate gather, c/h update.
// Output projection fused: lagged atomicAdd of h_{t-1} (reuses hb[]),
// 8 lanes (g==0) per cell. x prefetched 2 macros (8 steps) ahead via a
// triple-buffered float4 ring -> vmcnt wait never exposes load or atomic
// latency (in-order retirement; atomics are issued after the loads).
// ---------------------------------------------------------------------------
template<int ST>
__device__ __forceinline__ void rec_body(
    const float* __restrict__ x,    // [B,T,8] layer input
    const float* __restrict__ Wih,  // [32,8]
    const float* __restrict__ Whh,  // [32,8]
    const float* __restrict__ bias, // [32]
    const float* __restrict__ Wp,   // [8,16] output linear
    int dcol,                       // 0 fwd, 8 bwd (column block in Wp)
    float* __restrict__ y,          // [B,T,8], pre-inited with bias
    int b0)                         // batch of first cell in this wave
{
    const int tid = threadIdx.x;
    const int r   = tid & 31;
    const int j   = r >> 2;
    const int g   = r & 3;
    const int b   = b0 + (tid >> 5);
    const int row = g * 8 + j;

    const float NL2E = -1.4426950408889634f;
    const float gs   = (g == 2) ? (2.0f * NL2E) : NL2E;

    float Wi[8], Wh[8], Wc[8];
    #pragma unroll
    for (int k = 0; k < 8; ++k) {
        Wi[k] = Wih[row * 8 + k] * gs;
        Wh[k] = Whh[row * 8 + k] * gs;
        Wc[k] = Wp[j * 16 + dcol + k];
    }
    const float bz   = bias[row] * gs;
    const float asel = (g == 2) ? 2.0f : 1.0f;
    const float bsel = (g == 2) ? -1.0f : 0.0f;

    int hbA[8];  // bpermute byte-addresses: gate-0 lane of unit k, own cell half
    #pragma unroll
    for (int k = 0; k < 8; ++k) hbA[k] = ((tid & 32) + 4 * k) << 2;

    const int start = (ST > 0) ? 0 : (T_LEN - 1);
    const float* xp = x + ((long)b * T_LEN + start) * 8;
    float*       wp = y + ((long)b * T_LEN + start) * 8 + j;

    float c = 0.0f, h = 0.0f;
    float4 A[8], B[8], C[8];   // triple-buffered ring, 1 macro (4 steps) each

    auto loadm = [&](float4* dst) {
        #pragma unroll
        for (int s = 0; s < 4; ++s) {
            dst[2 * s]     = *(const float4*)(xp + ST * s * 8);
            dst[2 * s + 1] = *(const float4*)(xp + ST * s * 8 + 4);
        }
        xp += ST * 32;
    };

    auto step = [&](float4 xa, float4 xb, bool doProj) {
        // h broadcast (h_{t-1}) — the only DS round on the chain
        float hb[8];
        #pragma unroll
        for (int k = 0; k < 8; ++k) hb[k] = bperm(hbA[k], h);

        // input projection (independent of h; overlaps DS latency)
        float u0 = fmaf(Wi[0], xa.x, bz);
        u0 = fmaf(Wi[1], xa.y, u0);
        u0 = fmaf(Wi[2], xa.z, u0);
        u0 = fmaf(Wi[3], xa.w, u0);
        float u1 = Wi[4] * xb.x;
        u1 = fmaf(Wi[5], xb.y, u1);
        u1 = fmaf(Wi[6], xb.z, u1);
        u1 = fmaf(Wi[7], xb.w, u1);

        // fused output projection of h_{t-1} (off-chain, fire-and-forget)
        if (doProj) {
            float ctb = hb[0] * Wc[0];
            ctb = fmaf(hb[1], Wc[1], ctb);
            ctb = fmaf(hb[2], Wc[2], ctb);
            ctb = fmaf(hb[3], Wc[3], ctb);
            ctb = fmaf(hb[4], Wc[4], ctb);
            ctb = fmaf(hb[5], Wc[5], ctb);
            ctb = fmaf(hb[6], Wc[6], ctb);
            ctb = fmaf(hb[7], Wc[7], ctb);
            if (g == 0) atomicAdd(wp, ctb);
            wp += ST * 8;
        }

        // hidden matvec (two parallel chains)
        float a0 = fmaf(Wh[0], hb[0], u0);
        a0 = fmaf(Wh[1], hb[1], a0);
        a0 = fmaf(Wh[2], hb[2], a0);
        a0 = fmaf(Wh[3], hb[3], a0);
        float a1 = fmaf(Wh[4], hb[4], u1);
        a1 = fmaf(Wh[5], hb[5], a1);
        a1 = fmaf(Wh[6], hb[6], a1);
        a1 = fmaf(Wh[7], hb[7], a1);
        const float z = a0 + a1;

        // activation: sigma / tanh via rcp(1+exp2(pre-scaled z))
        const float val = fmaf(frcp(1.0f + fexp2(z)), asel, bsel);

        // gate gather within the quad (VALU pipe, ~4 cyc each)
        const float si = dppq<0x00>(val);
        const float sf = dppq<0x55>(val);
        const float gg = dppq<0xAA>(val);
        const float so = dppq<0xFF>(val);

        c = fmaf(sf, c, si * gg);
        const float th = fmaf(frcp(1.0f + fexp2(c * (2.0f * NL2E))), 2.0f, -1.0f);
        h = so * th;
    };

    auto macro4 = [&](float4* U, bool projFirst) {
        step(U[0], U[1], projFirst);
        step(U[2], U[3], true);
        step(U[4], U[5], true);
        step(U[6], U[7], true);
    };

    // prime: A <- macro 0, B <- macro 1
    loadm(A);
    loadm(B);

    // macro 0: use A, load C (macro 2); step 0 has no projection (h_{-1}=0)
    loadm(C);
    macro4(A, false);

    // macros 1..1020 (load always 2 macros ahead)
    for (int i = 0; i < 340; ++i) {
        loadm(A); macro4(B, true);
        loadm(B); macro4(C, true);
        loadm(C); macro4(A, true);
    }
    // macro 1021: use B, load A <- macro 1023
    loadm(A); macro4(B, true);
    // macro 1022: use C; macro 1023: use A (no more loads)
    macro4(C, true);
    macro4(A, true);

    // tail: project the final h
    {
        float hb[8];
        #pragma unroll
        for (int k = 0; k < 8; ++k) hb[k] = bperm(hbA[k], h);
        float ctb = hb[0] * Wc[0];
        #pragma unroll
        for (int k = 1; k < 8; ++k) ctb = fmaf(hb[k], Wc[k], ctb);
        if (g == 0) atomicAdd(wp, ctb);
    }
}

__global__ __launch_bounds__(64, 1)
void lstm_rec_kernel(const float* __restrict__ x,
                     const float* __restrict__ WihF, const float* __restrict__ WhhF,
                     const float* __restrict__ bF,
                     const float* __restrict__ WihB, const float* __restrict__ WhhB,
                     const float* __restrict__ bB,
                     const float* __restrict__ Wp,
                     float* __restrict__ y)
{
    if (blockIdx.x < 128)
        rec_body<1 >(x, WihF, WhhF, bF, Wp, 0, y, 2 * (int)blockIdx.x);
    else
        rec_body<-1>(x, WihB, WhhB, bB, Wp, 8, y, 2 * ((int)blockIdx.x - 128));
}

extern "C" void kernel_launch(void* const* d_in, const int* in_sizes, int n_in,
                              void* d_out, int out_size, void* d_ws, size_t ws_size,
                              hipStream_t stream)
{
    const float* x     = (const float*)d_in[0];
    const float* Wih1f = (const float*)d_in[1];
    const float* Whh1f = (const float*)d_in[2];
    const float* b1f   = (const float*)d_in[3];
    const float* Wih1b = (const float*)d_in[4];
    const float* Whh1b = (const float*)d_in[5];
    const float* b1b   = (const float*)d_in[6];
    const float* Wih2f = (const float*)d_in[7];
    const float* Whh2f = (const float*)d_in[8];
    const float* b2f   = (const float*)d_in[9];
    const float* Wih2b = (const float*)d_in[10];
    const float* Whh2b = (const float*)d_in[11];
    const float* b2b   = (const float*)d_in[12];
    const float* W1    = (const float*)d_in[13];
    const float* bl1   = (const float*)d_in[14];
    const float* W2    = (const float*)d_in[15];
    const float* bl2   = (const float*)d_in[16];

    float* out = (float*)d_out;
    float* y1  = (float*)d_ws;   // [B,T,8] fp32 = 32 MB (proven-safe ws budget)

    const int BT = B_SZ * T_LEN;

    init_bias_kernel<<<BT / 256, 256, 0, stream>>>(bl1, bl2, y1, out);

    lstm_rec_kernel<<<256, 64, 0, stream>>>(x, Wih1f, Whh1f, b1f,
                                            Wih1b, Whh1b, b1b, W1, y1);

    lstm_rec_kernel<<<256, 64, 0, stream>>>(y1, Wih2f, Whh2f, b2f,
                                            Wih2b, Whh2b, b2b, W2, out);
}

// Round 5
// 1316.700 us; speedup vs baseline: 2.5793x; 1.1393x over previous
//
#include <hip/hip_runtime.h>

#define T_LEN 4096
#define B_SZ  256

typedef float v2f __attribute__((ext_vector_type(2)));

__device__ __forceinline__ float fexp2(float x) { return __builtin_amdgcn_exp2f(x); }
__device__ __forceinline__ float frcp(float x)  { return __builtin_amdgcn_rcpf(x); }

// DPP row_ror:S (S=1..15): lane l <- lane (l-S)&15 within its 16-lane row.
template<int S>
__device__ __forceinline__ float rorN(float v) {
    return __int_as_float(__builtin_amdgcn_update_dpp(
        0, __float_as_int(v), 0x120 + S, 0xf, 0xf, true));
}

// ---------------------------------------------------------------------------
// Init: y1 <- bl1 broadcast, out <- bl2 broadcast. Recurrent kernels
// atomic-add their projected h contributions on top.
// ---------------------------------------------------------------------------
__global__ void init_bias_kernel(const float* __restrict__ bl1,
                                 const float* __restrict__ bl2,
                                 float* __restrict__ y1,
                                 float* __restrict__ out)
{
    const long idx = (long)blockIdx.x * blockDim.x + threadIdx.x; // over B*T
    float4 a1 = make_float4(bl1[0], bl1[1], bl1[2], bl1[3]);
    float4 b1 = make_float4(bl1[4], bl1[5], bl1[6], bl1[7]);
    float4 a2 = make_float4(bl2[0], bl2[1], bl2[2], bl2[3]);
    float4 b2 = make_float4(bl2[4], bl2[5], bl2[6], bl2[7]);
    float4* y4 = (float4*)y1;
    float4* o4 = (float4*)out;
    y4[idx * 2 + 0] = a1;
    y4[idx * 2 + 1] = b1;
    o4[idx * 2 + 0] = a2;
    o4[idx * 2 + 1] = b2;
}

// ---------------------------------------------------------------------------
// Recurrence, one direction (ST=+1 fwd / -1 bwd). 16 lanes per cell, 4 cells
// per wave. Lane cl: unit j=cl&7, half=cl>>3. Each lane computes TWO gate
// rows packed <2 x float>: half0 -> (i_j, f_j), half1 -> (g_j, o_j).
// h is period-8 replicated over the 16-lane row, so v_mov_dpp row_ror:s
// (pure VALU, ~4cyc) replaces the round-4 ds_bpermute broadcast (~180cyc
// incl. lgkmcnt stall). Hidden matvec: 8 pk_fma over the 8 rotations with
// per-lane weights pre-permuted by (j-s)&7. Both halves derive identical
// c,h (gate exchange = one row_ror:8 per value + cndmask). The fused output
// projection reuses the same rotations of h_{t-1} (8 scalar fma), atomicAdd
// from the 8 half0 lanes. x via triple-buffered register ring, prefetch 2
// macros (8 steps) ahead.
// ---------------------------------------------------------------------------
template<int ST>
__device__ __forceinline__ void rec_body(
    const float* __restrict__ x,    // [B,T,8] layer input
    const float* __restrict__ Wih,  // [32,8]
    const float* __restrict__ Whh,  // [32,8]
    const float* __restrict__ bias, // [32]
    const float* __restrict__ Wp,   // [8,16] output linear
    int dcol,                       // 0 fwd, 8 bwd
    float* __restrict__ y,          // [B,T,8], pre-inited with bias
    int b0)                         // batch of first cell in this wave
{
    const int tid  = threadIdx.x;
    const int cl   = tid & 15;
    const int j    = cl & 7;
    const int half = cl >> 3;
    const int b    = b0 + (tid >> 4);

    const int rA = half * 16 + j;        // half0: i-row j   | half1: g-row 16+j
    const int rB = half * 16 + 8 + j;    // half0: f-row 8+j | half1: o-row 24+j

    const float NL2E = -1.4426950408889634f;
    const float GSC  = 2.0f * NL2E;
    const float sA   = half ? GSC : NL2E;  // g-row gets tanh pre-scale
    const float sB   = NL2E;
    const float aselA = half ? 2.0f : 1.0f;   // tanh(u)=2*sigma(2u)-1 on vA/half1
    const float bselA = half ? -1.0f : 0.0f;

    // Per-lane constants: matvec weights permuted by rotation index.
    v2f Whk[8], Wik[8];
    float Wcp[8];
    #pragma unroll
    for (int s = 0; s < 8; ++s) {
        const int k = (j - s) & 7;
        Whk[s] = (v2f){Whh[rA * 8 + k] * sA, Whh[rB * 8 + k] * sB};
        Wcp[s] = Wp[j * 16 + dcol + k];
    }
    #pragma unroll
    for (int k = 0; k < 8; ++k)
        Wik[k] = (v2f){Wih[rA * 8 + k] * sA, Wih[rB * 8 + k] * sB};
    const v2f bpk = (v2f){bias[rA] * sA, bias[rB] * sB};

    const int start = (ST > 0) ? 0 : (T_LEN - 1);
    const float* xp = x + ((long)b * T_LEN + start) * 8;
    float*       wp = y + ((long)b * T_LEN + start) * 8 + j;

    float c = 0.0f, h = 0.0f;
    float4 A[8], B[8], C[8];   // ring: 1 macro (4 steps) each, 2 float4/step

    auto loadm = [&](float4* dst) {
        #pragma unroll
        for (int s = 0; s < 4; ++s) {
            dst[2 * s]     = *(const float4*)(xp + ST * s * 8);
            dst[2 * s + 1] = *(const float4*)(xp + ST * s * 8 + 4);
        }
        xp += ST * 32;
    };

    auto step = [&](float4 xa, float4 xb, bool doProj) {
        // input projection (no h dependence; fills issue while h settles)
        v2f ip = bpk;
        ip = __builtin_elementwise_fma(Wik[0], (v2f){xa.x, xa.x}, ip);
        ip = __builtin_elementwise_fma(Wik[1], (v2f){xa.y, xa.y}, ip);
        ip = __builtin_elementwise_fma(Wik[2], (v2f){xa.z, xa.z}, ip);
        ip = __builtin_elementwise_fma(Wik[3], (v2f){xa.w, xa.w}, ip);
        ip = __builtin_elementwise_fma(Wik[4], (v2f){xb.x, xb.x}, ip);
        ip = __builtin_elementwise_fma(Wik[5], (v2f){xb.y, xb.y}, ip);
        ip = __builtin_elementwise_fma(Wik[6], (v2f){xb.z, xb.z}, ip);
        ip = __builtin_elementwise_fma(Wik[7], (v2f){xb.w, xb.w}, ip);

        // 7 independent VALU rotations of h (h_{t-1}), all-lane valid
        float hr0 = h;
        float hr1 = rorN<1>(h);
        float hr2 = rorN<2>(h);
        float hr3 = rorN<3>(h);
        float hr4 = rorN<4>(h);
        float hr5 = rorN<5>(h);
        float hr6 = rorN<6>(h);
        float hr7 = rorN<7>(h);

        // hidden matvec: two parallel pk chains, one seeded with input proj
        v2f a0 = ip, a1 = {0.0f, 0.0f};
        a0 = __builtin_elementwise_fma(Whk[0], (v2f){hr0, hr0}, a0);
        a1 = __builtin_elementwise_fma(Whk[1], (v2f){hr1, hr1}, a1);
        a0 = __builtin_elementwise_fma(Whk[2], (v2f){hr2, hr2}, a0);
        a1 = __builtin_elementwise_fma(Whk[3], (v2f){hr3, hr3}, a1);
        a0 = __builtin_elementwise_fma(Whk[4], (v2f){hr4, hr4}, a0);
        a1 = __builtin_elementwise_fma(Whk[5], (v2f){hr5, hr5}, a1);
        a0 = __builtin_elementwise_fma(Whk[6], (v2f){hr6, hr6}, a0);
        a1 = __builtin_elementwise_fma(Whk[7], (v2f){hr7, hr7}, a1);
        const v2f z = a0 + a1;

        // fused output projection of h_{t-1} (reuses the rotations, off-chain)
        if (doProj) {
            float pa = hr0 * Wcp[0];
            pa = fmaf(hr1, Wcp[1], pa);
            pa = fmaf(hr2, Wcp[2], pa);
            pa = fmaf(hr3, Wcp[3], pa);
            pa = fmaf(hr4, Wcp[4], pa);
            pa = fmaf(hr5, Wcp[5], pa);
            pa = fmaf(hr6, Wcp[6], pa);
            pa = fmaf(hr7, Wcp[7], pa);
            if ((tid & 8) == 0) atomicAdd(wp, pa);
            wp += ST * 8;
        }

        // activations
        const float vA = fmaf(frcp(1.0f + fexp2(z.x)), aselA, bselA);
        const float vB = frcp(1.0f + fexp2(z.y));

        // cross-half gate exchange (row_ror:8 = swap halves within the 16-ring)
        const float pAx = rorN<8>(vA);
        const float pBx = rorN<8>(vB);
        const float gi = half ? pAx : vA;
        const float gf = half ? pBx : vB;
        const float gg = half ? vA  : pAx;
        const float go = half ? vB  : pBx;

        c = fmaf(gf, c, gi * gg);
        const float th = fmaf(frcp(1.0f + fexp2(c * GSC)), 2.0f, -1.0f);
        h = go * th;
    };

    auto macro4 = [&](float4* U, bool projFirst) {
        step(U[0], U[1], projFirst);
        step(U[2], U[3], true);
        step(U[4], U[5], true);
        step(U[6], U[7], true);
    };

    // prime: A <- macro 0, B <- macro 1
    loadm(A);
    loadm(B);

    // macro 0 (h_{-1}=0: no projection on the very first step)
    loadm(C);
    macro4(A, false);

    // macros 1..1020
    for (int i = 0; i < 340; ++i) {
        loadm(A); macro4(B, true);
        loadm(B); macro4(C, true);
        loadm(C); macro4(A, true);
    }
    loadm(A); macro4(B, true);   // macro 1021 (loads macro 1023)
    macro4(C, true);             // macro 1022
    macro4(A, true);             // macro 1023

    // tail: projection of the final h
    {
        float hr0 = h;
        float pa = hr0 * Wcp[0];
        pa = fmaf(rorN<1>(h), Wcp[1], pa);
        pa = fmaf(rorN<2>(h), Wcp[2], pa);
        pa = fmaf(rorN<3>(h), Wcp[3], pa);
        pa = fmaf(rorN<4>(h), Wcp[4], pa);
        pa = fmaf(rorN<5>(h), Wcp[5], pa);
        pa = fmaf(rorN<6>(h), Wcp[6], pa);
        pa = fmaf(rorN<7>(h), Wcp[7], pa);
        if ((tid & 8) == 0) atomicAdd(wp, pa);
    }
}

__global__ __launch_bounds__(64, 1)
void lstm_rec_kernel(const float* __restrict__ x,
                     const float* __restrict__ WihF, const float* __restrict__ WhhF,
                     const float* __restrict__ bF,
                     const float* __restrict__ WihB, const float* __restrict__ WhhB,
                     const float* __restrict__ bB,
                     const float* __restrict__ Wp,
                     float* __restrict__ y)
{
    if (blockIdx.x < 64)
        rec_body<1 >(x, WihF, WhhF, bF, Wp, 0, y, 4 * (int)blockIdx.x);
    else
        rec_body<-1>(x, WihB, WhhB, bB, Wp, 8, y, 4 * ((int)blockIdx.x - 64));
}

extern "C" void kernel_launch(void* const* d_in, const int* in_sizes, int n_in,
                              void* d_out, int out_size, void* d_ws, size_t ws_size,
                              hipStream_t stream)
{
    const float* x     = (const float*)d_in[0];
    const float* Wih1f = (const float*)d_in[1];
    const float* Whh1f = (const float*)d_in[2];
    const float* b1f   = (const float*)d_in[3];
    const float* Wih1b = (const float*)d_in[4];
    const float* Whh1b = (const float*)d_in[5];
    const float* b1b   = (const float*)d_in[6];
    const float* Wih2f = (const float*)d_in[7];
    const float* Whh2f = (const float*)d_in[8];
    const float* b2f   = (const float*)d_in[9];
    const float* Wih2b = (const float*)d_in[10];
    const float* Whh2b = (const float*)d_in[11];
    const float* b2b   = (const float*)d_in[12];
    const float* W1    = (const float*)d_in[13];
    const float* bl1   = (const float*)d_in[14];
    const float* W2    = (const float*)d_in[15];
    const float* bl2   = (const float*)d_in[16];

    float* out = (float*)d_out;
    float* y1  = (float*)d_ws;   // [B,T,8] fp32 = 32 MB (proven-safe ws budget)

    const int BT = B_SZ * T_LEN;

    init_bias_kernel<<<BT / 256, 256, 0, stream>>>(bl1, bl2, y1, out);

    lstm_rec_kernel<<<128, 64, 0, stream>>>(x, Wih1f, Whh1f, b1f,
                                            Wih1b, Whh1b, b1b, W1, y1);

    lstm_rec_kernel<<<128, 64, 0, stream>>>(y1, Wih2f, Whh2f, b2f,
                                            Wih2b, Whh2b, b2b, W2, out);
}

// Round 6
// 1315.244 us; speedup vs baseline: 2.5822x; 1.0011x over previous
//
#include <hip/hip_runtime.h>

#define T_LEN 4096
#define B_SZ  256

typedef float v2f __attribute__((ext_vector_type(2)));

__device__ __forceinline__ float fexp2(float x) { return __builtin_amdgcn_exp2f(x); }
__device__ __forceinline__ float frcp(float x)  { return __builtin_amdgcn_rcpf(x); }

// DPP row_ror:S (S=1..15): lane l <- lane (l-S)&15 within its 16-lane row.
template<int S>
__device__ __forceinline__ float rorN(float v) {
    return __int_as_float(__builtin_amdgcn_update_dpp(
        0, __float_as_int(v), 0x120 + S, 0xf, 0xf, true));
}

// ---------------------------------------------------------------------------
// Init: y1 <- bl1 broadcast, out <- bl2 broadcast. Recurrent kernels
// atomic-add their projected h contributions on top.
// ---------------------------------------------------------------------------
__global__ void init_bias_kernel(const float* __restrict__ bl1,
                                 const float* __restrict__ bl2,
                                 float* __restrict__ y1,
                                 float* __restrict__ out)
{
    const long idx = (long)blockIdx.x * blockDim.x + threadIdx.x; // over B*T
    float4 a1 = make_float4(bl1[0], bl1[1], bl1[2], bl1[3]);
    float4 b1 = make_float4(bl1[4], bl1[5], bl1[6], bl1[7]);
    float4 a2 = make_float4(bl2[0], bl2[1], bl2[2], bl2[3]);
    float4 b2 = make_float4(bl2[4], bl2[5], bl2[6], bl2[7]);
    float4* y4 = (float4*)y1;
    float4* o4 = (float4*)out;
    y4[idx * 2 + 0] = a1;
    y4[idx * 2 + 1] = b1;
    o4[idx * 2 + 0] = a2;
    o4[idx * 2 + 1] = b2;
}

// ---------------------------------------------------------------------------
// Recurrence, one direction (ST=+1 fwd / -1 bwd). 16 lanes per cell, 4 cells
// per wave, 128 blocks x 64 threads. Lane cl: unit j=cl&7, half=cl>>3.
// Each lane computes TWO gate rows packed <2 x float>: half0 -> (i_j, f_j),
// half1 -> (g_j, o_j). h is period-8 replicated over the 16-lane row, so
// v_mov_dpp row_ror:s (pure VALU) does the h broadcast; no LDS on the chain.
//
// ROUND-6 CHANGE: the x prefetch ring is 24 *named* float4 registers
// (no arrays / no address-taking -> guaranteed SROA) and each load group is
// pinned in program order with sched_barrier(0) so the scheduler cannot sink
// the loads to their uses (round-5 VGPR=92 proved it did exactly that,
// exposing ~200 cyc of load latency per step). Lookahead = 2 macros
// (8 steps); the per-step atomics are issued after the awaited loads, so
// in-order vmcnt retirement never waits on them.
// ---------------------------------------------------------------------------
template<int ST>
__device__ __forceinline__ void rec_body(
    const float* __restrict__ x,    // [B,T,8] layer input
    const float* __restrict__ Wih,  // [32,8]
    const float* __restrict__ Whh,  // [32,8]
    const float* __restrict__ bias, // [32]
    const float* __restrict__ Wp,   // [8,16] output linear
    int dcol,                       // 0 fwd, 8 bwd
    float* __restrict__ y,          // [B,T,8], pre-inited with bias
    int b0)                         // batch of first cell in this wave
{
    const int tid  = threadIdx.x;
    const int cl   = tid & 15;
    const int j    = cl & 7;
    const int half = cl >> 3;
    const int b    = b0 + (tid >> 4);

    const int rA = half * 16 + j;        // half0: i-row j   | half1: g-row 16+j
    const int rB = half * 16 + 8 + j;    // half0: f-row 8+j | half1: o-row 24+j

    const float NL2E = -1.4426950408889634f;
    const float GSC  = 2.0f * NL2E;
    const float sA   = half ? GSC : NL2E;     // g-row gets tanh pre-scale
    const float sB   = NL2E;
    const float aselA = half ? 2.0f : 1.0f;   // tanh(u)=2*sigma(2u)-1 on half1
    const float bselA = half ? -1.0f : 0.0f;

    // Per-lane constants: matvec weights permuted by rotation index.
    v2f Whk[8], Wik[8];
    float Wcp[8];
    #pragma unroll
    for (int s = 0; s < 8; ++s) {
        const int k = (j - s) & 7;
        Whk[s] = (v2f){Whh[rA * 8 + k] * sA, Whh[rB * 8 + k] * sB};
        Wcp[s] = Wp[j * 16 + dcol + k];
    }
    #pragma unroll
    for (int k = 0; k < 8; ++k)
        Wik[k] = (v2f){Wih[rA * 8 + k] * sA, Wih[rB * 8 + k] * sB};
    const v2f bpk = (v2f){bias[rA] * sA, bias[rB] * sB};

    const int start = (ST > 0) ? 0 : (T_LEN - 1);
    const float* xp = x + ((long)b * T_LEN + start) * 8;
    float*       wp = y + ((long)b * T_LEN + start) * 8 + j;

    float c = 0.0f, h = 0.0f;

    auto step = [&](float4 xa, float4 xb, bool doProj) {
        // input projection (no h dependence; fills issue while h settles)
        v2f ip = bpk;
        ip = __builtin_elementwise_fma(Wik[0], (v2f){xa.x, xa.x}, ip);
        ip = __builtin_elementwise_fma(Wik[1], (v2f){xa.y, xa.y}, ip);
        ip = __builtin_elementwise_fma(Wik[2], (v2f){xa.z, xa.z}, ip);
        ip = __builtin_elementwise_fma(Wik[3], (v2f){xa.w, xa.w}, ip);
        ip = __builtin_elementwise_fma(Wik[4], (v2f){xb.x, xb.x}, ip);
        ip = __builtin_elementwise_fma(Wik[5], (v2f){xb.y, xb.y}, ip);
        ip = __builtin_elementwise_fma(Wik[6], (v2f){xb.z, xb.z}, ip);
        ip = __builtin_elementwise_fma(Wik[7], (v2f){xb.w, xb.w}, ip);

        // 7 independent VALU rotations of h (h_{t-1})
        float hr0 = h;
        float hr1 = rorN<1>(h);
        float hr2 = rorN<2>(h);
        float hr3 = rorN<3>(h);
        float hr4 = rorN<4>(h);
        float hr5 = rorN<5>(h);
        float hr6 = rorN<6>(h);
        float hr7 = rorN<7>(h);

        // hidden matvec: two parallel pk chains, one seeded with input proj
        v2f a0 = ip, a1 = {0.0f, 0.0f};
        a0 = __builtin_elementwise_fma(Whk[0], (v2f){hr0, hr0}, a0);
        a1 = __builtin_elementwise_fma(Whk[1], (v2f){hr1, hr1}, a1);
        a0 = __builtin_elementwise_fma(Whk[2], (v2f){hr2, hr2}, a0);
        a1 = __builtin_elementwise_fma(Whk[3], (v2f){hr3, hr3}, a1);
        a0 = __builtin_elementwise_fma(Whk[4], (v2f){hr4, hr4}, a0);
        a1 = __builtin_elementwise_fma(Whk[5], (v2f){hr5, hr5}, a1);
        a0 = __builtin_elementwise_fma(Whk[6], (v2f){hr6, hr6}, a0);
        a1 = __builtin_elementwise_fma(Whk[7], (v2f){hr7, hr7}, a1);
        const v2f z = a0 + a1;

        // fused output projection of h_{t-1} (reuses the rotations, off-chain)
        if (doProj) {
            float pa = hr0 * Wcp[0];
            pa = fmaf(hr1, Wcp[1], pa);
            pa = fmaf(hr2, Wcp[2], pa);
            pa = fmaf(hr3, Wcp[3], pa);
            pa = fmaf(hr4, Wcp[4], pa);
            pa = fmaf(hr5, Wcp[5], pa);
            pa = fmaf(hr6, Wcp[6], pa);
            pa = fmaf(hr7, Wcp[7], pa);
            if ((tid & 8) == 0) atomicAdd(wp, pa);
            wp += ST * 8;
        }

        // activations
        const float vA = fmaf(frcp(1.0f + fexp2(z.x)), aselA, bselA);
        const float vB = frcp(1.0f + fexp2(z.y));

        // cross-half gate exchange (row_ror:8 swaps the two 8-lane halves)
        const float pAx = rorN<8>(vA);
        const float pBx = rorN<8>(vB);
        const float gi = half ? pAx : vA;
        const float gf = half ? pBx : vB;
        const float gg = half ? vA  : pAx;
        const float go = half ? vB  : pBx;

        c = fmaf(gf, c, gi * gg);
        const float th = fmaf(frcp(1.0f + fexp2(c * GSC)), 2.0f, -1.0f);
        h = go * th;
    };

    // Named prefetch buffers: 3 macros (4 steps = 8 float4 each).
    float4 A0, A1, A2, A3, A4, A5, A6, A7;
    float4 B0, B1, B2, B3, B4, B5, B6, B7;
    float4 C0, C1, C2, C3, C4, C5, C6, C7;

#define LOADM(P0, P1, P2, P3, P4, P5, P6, P7)                                  \
    P0 = *(const float4*)(xp);                                                 \
    P1 = *(const float4*)(xp + 4);                                             \
    P2 = *(const float4*)(xp + ST * 8);                                        \
    P3 = *(const float4*)(xp + ST * 8 + 4);                                    \
    P4 = *(const float4*)(xp + ST * 16);                                       \
    P5 = *(const float4*)(xp + ST * 16 + 4);                                   \
    P6 = *(const float4*)(xp + ST * 24);                                       \
    P7 = *(const float4*)(xp + ST * 24 + 4);                                   \
    xp += ST * 32;                                                             \
    __builtin_amdgcn_sched_barrier(0);

#define MACRO4(P0, P1, P2, P3, P4, P5, P6, P7, FIRSTPROJ)                      \
    step(P0, P1, FIRSTPROJ);                                                   \
    step(P2, P3, true);                                                        \
    step(P4, P5, true);                                                        \
    step(P6, P7, true);

    LOADM(A0, A1, A2, A3, A4, A5, A6, A7)                 // macro 0
    LOADM(B0, B1, B2, B3, B4, B5, B6, B7)                 // macro 1
    LOADM(C0, C1, C2, C3, C4, C5, C6, C7)                 // macro 2
    MACRO4(A0, A1, A2, A3, A4, A5, A6, A7, false)         // process 0

    for (int i = 0; i < 340; ++i) {                       // macros 1..1020
        LOADM(A0, A1, A2, A3, A4, A5, A6, A7)             // load 3i+3
        MACRO4(B0, B1, B2, B3, B4, B5, B6, B7, true)      // process 3i+1
        LOADM(B0, B1, B2, B3, B4, B5, B6, B7)             // load 3i+4
        MACRO4(C0, C1, C2, C3, C4, C5, C6, C7, true)      // process 3i+2
        LOADM(C0, C1, C2, C3, C4, C5, C6, C7)             // load 3i+5
        MACRO4(A0, A1, A2, A3, A4, A5, A6, A7, true)      // process 3i+3
    }
    // after loop: processed ..1020; B holds 1021, C holds 1022
    LOADM(A0, A1, A2, A3, A4, A5, A6, A7)                 // load 1023
    MACRO4(B0, B1, B2, B3, B4, B5, B6, B7, true)          // process 1021
    MACRO4(C0, C1, C2, C3, C4, C5, C6, C7, true)          // process 1022
    MACRO4(A0, A1, A2, A3, A4, A5, A6, A7, true)          // process 1023

#undef LOADM
#undef MACRO4

    // tail: projection of the final h
    {
        float pa = h * Wcp[0];
        pa = fmaf(rorN<1>(h), Wcp[1], pa);
        pa = fmaf(rorN<2>(h), Wcp[2], pa);
        pa = fmaf(rorN<3>(h), Wcp[3], pa);
        pa = fmaf(rorN<4>(h), Wcp[4], pa);
        pa = fmaf(rorN<5>(h), Wcp[5], pa);
        pa = fmaf(rorN<6>(h), Wcp[6], pa);
        pa = fmaf(rorN<7>(h), Wcp[7], pa);
        if ((tid & 8) == 0) atomicAdd(wp, pa);
    }
}

__global__ __launch_bounds__(64, 1)
void lstm_rec_kernel(const float* __restrict__ x,
                     const float* __restrict__ WihF, const float* __restrict__ WhhF,
                     const float* __restrict__ bF,
                     const float* __restrict__ WihB, const float* __restrict__ WhhB,
                     const float* __restrict__ bB,
                     const float* __restrict__ Wp,
                     float* __restrict__ y)
{
    if (blockIdx.x < 64)
        rec_body<1 >(x, WihF, WhhF, bF, Wp, 0, y, 4 * (int)blockIdx.x);
    else
        rec_body<-1>(x, WihB, WhhB, bB, Wp, 8, y, 4 * ((int)blockIdx.x - 64));
}

extern "C" void kernel_launch(void* const* d_in, const int* in_sizes, int n_in,
                              void* d_out, int out_size, void* d_ws, size_t ws_size,
                              hipStream_t stream)
{
    const float* x     = (const float*)d_in[0];
    const float* Wih1f = (const float*)d_in[1];
    const float* Whh1f = (const float*)d_in[2];
    const float* b1f   = (const float*)d_in[3];
    const float* Wih1b = (const float*)d_in[4];
    const float* Whh1b = (const float*)d_in[5];
    const float* b1b   = (const float*)d_in[6];
    const float* Wih2f = (const float*)d_in[7];
    const float* Whh2f = (const float*)d_in[8];
    const float* b2f   = (const float*)d_in[9];
    const float* Wih2b = (const float*)d_in[10];
    const float* Whh2b = (const float*)d_in[11];
    const float* b2b   = (const float*)d_in[12];
    const float* W1    = (const float*)d_in[13];
    const float* bl1   = (const float*)d_in[14];
    const float* W2    = (const float*)d_in[15];
    const float* bl2   = (const float*)d_in[16];

    float* out = (float*)d_out;
    float* y1  = (float*)d_ws;   // [B,T,8] fp32 = 32 MB (proven-safe ws budget)

    const int BT = B_SZ * T_LEN;

    init_bias_kernel<<<BT / 256, 256, 0, stream>>>(bl1, bl2, y1, out);

    lstm_rec_kernel<<<128, 64, 0, stream>>>(x, Wih1f, Whh1f, b1f,
                                            Wih1b, Whh1b, b1b, W1, y1);

    lstm_rec_kernel<<<128, 64, 0, stream>>>(y1, Wih2f, Whh2f, b2f,
                                            Wih2b, Whh2b, b2b, W2, out);
}

// Round 8
// 1098.880 us; speedup vs baseline: 3.0906x; 1.1969x over previous
//
#include <hip/hip_runtime.h>

#define T_LEN 4096
#define B_SZ  256

typedef float v2f __attribute__((ext_vector_type(2)));
typedef float v4f __attribute__((ext_vector_type(4)));

__device__ __forceinline__ float fexp2(float x) { return __builtin_amdgcn_exp2f(x); }
__device__ __forceinline__ float frcp(float x)  { return __builtin_amdgcn_rcpf(x); }

// DPP row_ror:S (S=1..15): lane l <- lane (l-S)&15 within its 16-lane row.
template<int S>
__device__ __forceinline__ float rorN(float v) {
    return __int_as_float(__builtin_amdgcn_update_dpp(
        0, __float_as_int(v), 0x120 + S, 0xf, 0xf, true));
}

// Inline-asm vm ops: the register allocator cannot rematerialize an asm
// result (round-5/6 VGPR=88..92 proved RA re-emits plain loads at their
// uses, exposing full memory latency every macro), and with an all-asm vm
// stream the outstanding-op counts for manual s_waitcnt are exact.
template<int OFF>
__device__ __forceinline__ v4f aload(const float* p) {
    v4f r;
    asm volatile("global_load_dwordx4 %0, %1, off offset:%2"
                 : "=v"(r) : "v"(p), "i"(OFF) : "memory");
    return r;
}
__device__ __forceinline__ void aatomic(float* p, float v) {
    asm volatile("global_atomic_add_f32 %0, %1, off"
                 :: "v"(p), "v"(v) : "memory");
}

// ---------------------------------------------------------------------------
// Init: y1 <- bl1 broadcast, out <- bl2 broadcast. Recurrent kernels
// atomic-add their projected h contributions on top.
// ---------------------------------------------------------------------------
__global__ void init_bias_kernel(const float* __restrict__ bl1,
                                 const float* __restrict__ bl2,
                                 float* __restrict__ y1,
                                 float* __restrict__ out)
{
    const long idx = (long)blockIdx.x * blockDim.x + threadIdx.x; // over B*T
    float4 a1 = make_float4(bl1[0], bl1[1], bl1[2], bl1[3]);
    float4 b1 = make_float4(bl1[4], bl1[5], bl1[6], bl1[7]);
    float4 a2 = make_float4(bl2[0], bl2[1], bl2[2], bl2[3]);
    float4 b2 = make_float4(bl2[4], bl2[5], bl2[6], bl2[7]);
    float4* y4 = (float4*)y1;
    float4* o4 = (float4*)out;
    y4[idx * 2 + 0] = a1;
    y4[idx * 2 + 1] = b1;
    o4[idx * 2 + 0] = a2;
    o4[idx * 2 + 1] = b2;
}

// ---------------------------------------------------------------------------
// Recurrence, one direction (ST=+1 fwd / -1 bwd). 16 lanes per cell, 4 cells
// per wave, 128 blocks x 64 threads. Lane cl: unit j=cl&7, half=cl>>3.
// Each lane computes TWO gate rows packed <2 x float>: half0 -> (i_j, f_j),
// half1 -> (g_j, o_j). h is period-8 replicated over the 16-lane row; DPP
// row_ror does the h broadcast (no LDS/DS on the chain). x arrives through
// an asm-load register ring (3 macros of 4 steps), lookahead 2 macros, with
// exact manual s_waitcnt vmcnt(N). Output projection fused as asm
// global_atomic_add_f32 of h_{t-1} from all lanes (Wc pre-halved; the two
// halves contribute pa/2 each).
// ---------------------------------------------------------------------------
template<int ST>
__device__ __forceinline__ void rec_body(
    const float* x,    // [B,T,8] layer input
    const float* Wih,  // [32,8]
    const float* Whh,  // [32,8]
    const float* bias, // [32]
    const float* Wp,   // [8,16] output linear
    int dcol,          // 0 fwd, 8 bwd
    float* y,          // [B,T,8], pre-inited with bias
    int b0)            // batch of first cell in this wave
{
    const int tid  = threadIdx.x;
    const int cl   = tid & 15;
    const int j    = cl & 7;
    const int half = cl >> 3;
    const int b    = b0 + (tid >> 4);

    const int rA = half * 16 + j;        // half0: i-row j   | half1: g-row 16+j
    const int rB = half * 16 + 8 + j;    // half0: f-row 8+j | half1: o-row 24+j

    const float NL2E = -1.4426950408889634f;
    const float GSC  = 2.0f * NL2E;
    const float sA   = half ? GSC : NL2E;     // g-row gets tanh pre-scale
    const float sB   = NL2E;
    const float aselA = half ? 2.0f : 1.0f;   // tanh(u)=2*sigma(2u)-1 on half1
    const float bselA = half ? -1.0f : 0.0f;

    // Per-lane constants: matvec weights permuted by rotation index.
    v2f Whk[8], Wik[8];
    float Wcp[8];
    #pragma unroll
    for (int s = 0; s < 8; ++s) {
        const int k = (j - s) & 7;
        Whk[s] = (v2f){Whh[rA * 8 + k] * sA, Whh[rB * 8 + k] * sB};
        Wcp[s] = Wp[j * 16 + dcol + k] * 0.5f;  // halved: both halves atomic
    }
    #pragma unroll
    for (int k = 0; k < 8; ++k)
        Wik[k] = (v2f){Wih[rA * 8 + k] * sA, Wih[rB * 8 + k] * sB};
    const v2f bpk = (v2f){bias[rA] * sA, bias[rB] * sB};

    const int start = (ST > 0) ? 0 : (T_LEN - 1);
    const float* xp = x + ((long)b * T_LEN + start) * 8;
    float*       wp = y + ((long)b * T_LEN + start) * 8 + j;

    float c = 0.0f, h = 0.0f;

    auto step = [&](v4f xa, v4f xb, bool doProj) {
        // input projection (no h dependence; fills issue while h settles)
        v2f ip = bpk;
        ip = __builtin_elementwise_fma(Wik[0], (v2f){xa.x, xa.x}, ip);
        ip = __builtin_elementwise_fma(Wik[1], (v2f){xa.y, xa.y}, ip);
        ip = __builtin_elementwise_fma(Wik[2], (v2f){xa.z, xa.z}, ip);
        ip = __builtin_elementwise_fma(Wik[3], (v2f){xa.w, xa.w}, ip);
        ip = __builtin_elementwise_fma(Wik[4], (v2f){xb.x, xb.x}, ip);
        ip = __builtin_elementwise_fma(Wik[5], (v2f){xb.y, xb.y}, ip);
        ip = __builtin_elementwise_fma(Wik[6], (v2f){xb.z, xb.z}, ip);
        ip = __builtin_elementwise_fma(Wik[7], (v2f){xb.w, xb.w}, ip);

        // 7 independent VALU rotations of h (h_{t-1})
        float hr0 = h;
        float hr1 = rorN<1>(h);
        float hr2 = rorN<2>(h);
        float hr3 = rorN<3>(h);
        float hr4 = rorN<4>(h);
        float hr5 = rorN<5>(h);
        float hr6 = rorN<6>(h);
        float hr7 = rorN<7>(h);

        // hidden matvec: two parallel pk chains, one seeded with input proj
        v2f a0 = ip, a1 = {0.0f, 0.0f};
        a0 = __builtin_elementwise_fma(Whk[0], (v2f){hr0, hr0}, a0);
        a1 = __builtin_elementwise_fma(Whk[1], (v2f){hr1, hr1}, a1);
        a0 = __builtin_elementwise_fma(Whk[2], (v2f){hr2, hr2}, a0);
        a1 = __builtin_elementwise_fma(Whk[3], (v2f){hr3, hr3}, a1);
        a0 = __builtin_elementwise_fma(Whk[4], (v2f){hr4, hr4}, a0);
        a1 = __builtin_elementwise_fma(Whk[5], (v2f){hr5, hr5}, a1);
        a0 = __builtin_elementwise_fma(Whk[6], (v2f){hr6, hr6}, a0);
        a1 = __builtin_elementwise_fma(Whk[7], (v2f){hr7, hr7}, a1);
        const v2f z = a0 + a1;

        // fused output projection of h_{t-1} (off-chain); all 64 lanes
        // atomic with halved Wcp (two halves sum to the full contribution)
        if (doProj) {
            float pa = hr0 * Wcp[0];
            pa = fmaf(hr1, Wcp[1], pa);
            pa = fmaf(hr2, Wcp[2], pa);
            pa = fmaf(hr3, Wcp[3], pa);
            pa = fmaf(hr4, Wcp[4], pa);
            pa = fmaf(hr5, Wcp[5], pa);
            pa = fmaf(hr6, Wcp[6], pa);
            pa = fmaf(hr7, Wcp[7], pa);
            aatomic(wp, pa);
            wp += ST * 8;
        }

        // activations
        const float vA = fmaf(frcp(1.0f + fexp2(z.x)), aselA, bselA);
        const float vB = frcp(1.0f + fexp2(z.y));

        // cross-half gate exchange (row_ror:8 swaps the two 8-lane halves)
        const float pAx = rorN<8>(vA);
        const float pBx = rorN<8>(vB);
        const float gi = half ? pAx : vA;
        const float gf = half ? pBx : vB;
        const float gg = half ? vA  : pAx;
        const float go = half ? vB  : pBx;

        c = fmaf(gf, c, gi * gg);
        const float th = fmaf(frcp(1.0f + fexp2(c * GSC)), 2.0f, -1.0f);
        h = go * th;
    };

    // Named prefetch ring: 3 macros x 4 steps (2 x v4f per step).
    v4f A0, A1, A2, A3, A4, A5, A6, A7;
    v4f B0, B1, B2, B3, B4, B5, B6, B7;
    v4f C0, C1, C2, C3, C4, C5, C6, C7;

#define AREGS A0, A1, A2, A3, A4, A5, A6, A7
#define BREGS B0, B1, B2, B3, B4, B5, B6, B7
#define CREGS C0, C1, C2, C3, C4, C5, C6, C7

// Inner 8-parameter macros + one indirection layer so that a register-set
// macro (AREGS/BREGS/CREGS) expands to 8 arguments before re-scanning.
#define LOADM_I(P0, P1, P2, P3, P4, P5, P6, P7)                                \
    P0 = aload<0>(xp);            P1 = aload<16>(xp);                          \
    P2 = aload<ST * 32>(xp);      P3 = aload<ST * 32 + 16>(xp);                \
    P4 = aload<ST * 64>(xp);      P5 = aload<ST * 64 + 16>(xp);                \
    P6 = aload<ST * 96>(xp);      P7 = aload<ST * 96 + 16>(xp);                \
    xp += ST * 32;
#define LOADM(REGS) LOADM_I(REGS)

#define WAITM_I(N, P0, P1, P2, P3, P4, P5, P6, P7)                             \
    asm volatile("s_waitcnt vmcnt(" #N ")"                                     \
        : "+v"(P0), "+v"(P1), "+v"(P2), "+v"(P3),                              \
          "+v"(P4), "+v"(P5), "+v"(P6), "+v"(P7) :: "memory")
#define WAITM(N, REGS) WAITM_I(N, REGS)

#define MACRO4_I(P0, P1, P2, P3, P4, P5, P6, P7, FIRSTPROJ)                    \
    step(P0, P1, FIRSTPROJ);                                                   \
    step(P2, P3, true);                                                        \
    step(P4, P5, true);                                                        \
    step(P6, P7, true);
#define MACRO4(REGS, FIRSTPROJ) MACRO4_I(REGS, FIRSTPROJ)

    // drain compiler-issued (weight) loads so asm vm counts are exact
    asm volatile("s_waitcnt vmcnt(0)" ::: "memory");

    LOADM(AREGS)                       // L0
    LOADM(BREGS)                       // L1
    LOADM(CREGS)                       // L2
    WAITM(16, AREGS); MACRO4(AREGS, false)    // M0 (3 atomics: h_{-1}=0)
    LOADM(AREGS)                       // L3
    WAITM(19, BREGS); MACRO4(BREGS, true)     // M1 (4 atomics)
    LOADM(BREGS)                       // L4
    WAITM(23, CREGS); MACRO4(CREGS, true)     // M2

    for (int i = 0; i < 339; ++i) {    // M3..M1019, loads L5..L1021
        LOADM(CREGS) WAITM(24, AREGS); MACRO4(AREGS, true)
        LOADM(AREGS) WAITM(24, BREGS); MACRO4(BREGS, true)
        LOADM(BREGS) WAITM(24, CREGS); MACRO4(CREGS, true)
    }
    LOADM(CREGS)                       // L1022
    WAITM(24, AREGS); MACRO4(AREGS, true)     // M1020
    LOADM(AREGS)                       // L1023
    WAITM(24, BREGS); MACRO4(BREGS, true)     // M1021
    WAITM(16, CREGS); MACRO4(CREGS, true)     // M1022
    WAITM(8,  AREGS); MACRO4(AREGS, true)     // M1023

#undef LOADM
#undef LOADM_I
#undef MACRO4
#undef MACRO4_I
#undef WAITM
#undef WAITM_I
#undef AREGS
#undef BREGS
#undef CREGS

    // tail: projection of the final h (all lanes, halved Wcp)
    {
        float pa = h * Wcp[0];
        pa = fmaf(rorN<1>(h), Wcp[1], pa);
        pa = fmaf(rorN<2>(h), Wcp[2], pa);
        pa = fmaf(rorN<3>(h), Wcp[3], pa);
        pa = fmaf(rorN<4>(h), Wcp[4], pa);
        pa = fmaf(rorN<5>(h), Wcp[5], pa);
        pa = fmaf(rorN<6>(h), Wcp[6], pa);
        pa = fmaf(rorN<7>(h), Wcp[7], pa);
        aatomic(wp, pa);
    }
}

__global__ __launch_bounds__(64, 1)
void lstm_rec_kernel(const float* __restrict__ x,
                     const float* __restrict__ WihF, const float* __restrict__ WhhF,
                     const float* __restrict__ bF,
                     const float* __restrict__ WihB, const float* __restrict__ WhhB,
                     const float* __restrict__ bB,
                     const float* __restrict__ Wp,
                     float* __restrict__ y)
{
    if (blockIdx.x < 64)
        rec_body<1 >(x, WihF, WhhF, bF, Wp, 0, y, 4 * (int)blockIdx.x);
    else
        rec_body<-1>(x, WihB, WhhB, bB, Wp, 8, y, 4 * ((int)blockIdx.x - 64));
}

extern "C" void kernel_launch(void* const* d_in, const int* in_sizes, int n_in,
                              void* d_out, int out_size, void* d_ws, size_t ws_size,
                              hipStream_t stream)
{
    const float* x     = (const float*)d_in[0];
    const float* Wih1f = (const float*)d_in[1];
    const float* Whh1f = (const float*)d_in[2];
    const float* b1f   = (const float*)d_in[3];
    const float* Wih1b = (const float*)d_in[4];
    const float* Whh1b = (const float*)d_in[5];
    const float* b1b   = (const float*)d_in[6];
    const float* Wih2f = (const float*)d_in[7];
    const float* Whh2f = (const float*)d_in[8];
    const float* b2f   = (const float*)d_in[9];
    const float* Wih2b = (const float*)d_in[10];
    const float* Whh2b = (const float*)d_in[11];
    const float* b2b   = (const float*)d_in[12];
    const float* W1    = (const float*)d_in[13];
    const float* bl1   = (const float*)d_in[14];
    const float* W2    = (const float*)d_in[15];
    const float* bl2   = (const float*)d_in[16];

    float* out = (float*)d_out;
    float* y1  = (float*)d_ws;   // [B,T,8] fp32 = 32 MB (proven-safe ws budget)

    const int BT = B_SZ * T_LEN;

    init_bias_kernel<<<BT / 256, 256, 0, stream>>>(bl1, bl2, y1, out);

    lstm_rec_kernel<<<128, 64, 0, stream>>>(x, Wih1f, Whh1f, b1f,
                                            Wih1b, Whh1b, b1b, W1, y1);

    lstm_rec_kernel<<<128, 64, 0, stream>>>(y1, Wih2f, Whh2f, b2f,
                                            Wih2b, Whh2b, b2b, W2, out);
}